// Round 4
// baseline (2355.839 us; speedup 1.0000x reference)
//
#include <hip/hip_runtime.h>
#include <hip/hip_bf16.h>
#include <stdint.h>

#define TT 4096
#define HH 4096
#define FF 14336
#define NCAT (2 * FF)   // 28672

typedef __attribute__((ext_vector_type(8))) short bf16x8;
typedef __attribute__((ext_vector_type(4))) float f32x4;

__device__ __forceinline__ unsigned short f32_to_bf16(float f) {
    union { float f; unsigned int u; } v; v.f = f;
    unsigned int r = v.u + 0x7FFFu + ((v.u >> 16) & 1u);  // RNE
    return (unsigned short)(r >> 16);
}

#define GLOAD16(g, l)                                                          \
    __builtin_amdgcn_global_load_lds(                                          \
        (const __attribute__((address_space(1))) void*)(g),                    \
        (__attribute__((address_space(3))) void*)(l), 16, 0, 0)

// ---------------- convert fp32 -> bf16, same layout ----------------
__global__ void cvt_lin(const float* __restrict__ in,
                        unsigned short* __restrict__ out, long n4) {
    long stride = (long)gridDim.x * blockDim.x;
    for (long i = (long)blockIdx.x * blockDim.x + threadIdx.x; i < n4; i += stride) {
        float4 v = *(const float4*)(in + i * 4);
        ushort4 o;
        o.x = f32_to_bf16(v.x); o.y = f32_to_bf16(v.y);
        o.z = f32_to_bf16(v.z); o.w = f32_to_bf16(v.w);
        *(ushort4*)(out + i * 4) = o;
    }
}

// ---- convert + transpose + interleave: in [H][F] fp32 -> wcat rows bf16 ----
// f-column f of `in` goes to wcat row ((f>>4)<<5) + (f&15) + off   (off=0 gate, 16 up)
__global__ void cvt_tri(const float* __restrict__ in,
                        unsigned short* __restrict__ out, int off) {
    __shared__ float tile[64][65];
    int bh = blockIdx.x & 63;   // H/64 = 64
    int bf = blockIdx.x >> 6;   // F/64 = 224
    int t = threadIdx.x;
    int r16 = t >> 4;           // 0..15
    int c4 = (t & 15) * 4;      // 0..60
#pragma unroll
    for (int it = 0; it < 4; ++it) {
        int h = r16 + it * 16;
        float4 v = *(const float4*)(in + (size_t)(bh * 64 + h) * FF + bf * 64 + c4);
        tile[h][c4 + 0] = v.x; tile[h][c4 + 1] = v.y;
        tile[h][c4 + 2] = v.z; tile[h][c4 + 3] = v.w;
    }
    __syncthreads();
#pragma unroll
    for (int it = 0; it < 4; ++it) {
        int f = r16 + it * 16;
        int fg = bf * 64 + f;
        int row_out = ((fg >> 4) << 5) + (fg & 15) + off;
        ushort4 o;
        o.x = f32_to_bf16(tile[c4 + 0][f]);
        o.y = f32_to_bf16(tile[c4 + 1][f]);
        o.z = f32_to_bf16(tile[c4 + 2][f]);
        o.w = f32_to_bf16(tile[c4 + 3][f]);
        *(ushort4*)(out + (size_t)row_out * HH + bh * 64 + c4) = o;
    }
}

// =================== 8-phase 256x256 GEMM core (BK=64, 8 waves) ============
// LDS: lsA[2buf][2mhalf][128][64]b16 (16KiB slots), lsB same. 128 KiB total.
// Swizzle: byte ^= ((row&6)<<4)  (applied to gload SOURCE and ds_read; LDS linear).
// Register-held fragments: each LDS fragment read exactly ONCE per K-step.
// Snake quadrant order: (m0n0)->(m1n0)->(m1n1)->(m0n1).
// Stage map (slot dead >=1 phase before overwrite): ph2<-A0, ph3<-B0, ph4<-A1+B1.
// Fence: vmcnt(8) at ph4/ph8 only (8 gloads = one K-step's stages stay in flight).

#define STG_A(BUF, SLOT, TILE) do {                                            \
    char* d_ = lsA + (((BUF)*2 + (SLOT)) << 14) + tid * 16;                    \
    GLOAD16(sA[SLOT][0] + (size_t)(TILE) * 64, d_);                            \
    GLOAD16(sA[SLOT][1] + (size_t)(TILE) * 64, d_ + 8192);                     \
  } while (0)

#define STG_B(BUF, SLOT, TILE) do {                                            \
    char* d_ = lsB + (((BUF)*2 + (SLOT)) << 14) + tid * 16;                    \
    GLOAD16(sB[SLOT][0] + (size_t)(TILE) * 64, d_);                            \
    GLOAD16(sB[SLOT][1] + (size_t)(TILE) * 64, d_ + 8192);                     \
  } while (0)

#define READ_A(DST, BUF, MQ) do {                                              \
    const char* pA_ = lsA + (((BUF)*2 + (MQ)) << 14);                          \
    _Pragma("unroll") for (int i_ = 0; i_ < 4; ++i_)                           \
    _Pragma("unroll") for (int k_ = 0; k_ < 2; ++k_)                           \
      DST[i_][k_] = *(const bf16x8*)(pA_ + ((((wr*64 + i_*16 + fr) << 7) + k_*64 + kg2) ^ lmask)); \
  } while (0)

#define READ_B(DST, BUF, NQ) do {                                              \
    const char* pB_ = lsB + (((BUF)*2 + (NQ)) << 14);                          \
    _Pragma("unroll") for (int j_ = 0; j_ < 2; ++j_)                           \
    _Pragma("unroll") for (int k_ = 0; k_ < 2; ++k_)                           \
      DST[j_][k_] = *(const bf16x8*)(pB_ + ((((wc*32 + j_*16 + fr) << 7) + k_*64 + kg2) ^ lmask)); \
  } while (0)

#define MFMA_Q(MQ, NQ, AF, BF)                                                 \
    _Pragma("unroll") for (int i_ = 0; i_ < 4; ++i_)                           \
    _Pragma("unroll") for (int j_ = 0; j_ < 2; ++j_)                           \
    _Pragma("unroll") for (int k_ = 0; k_ < 2; ++k_)                           \
      acc[MQ][i_][NQ][j_] = __builtin_amdgcn_mfma_f32_16x16x32_bf16(           \
          AF[i_][k_], BF[j_][k_], acc[MQ][i_][NQ][j_], 0, 0, 0)

#define BAR do {                                                               \
    asm volatile("" ::: "memory");                                             \
    __builtin_amdgcn_s_barrier();                                              \
    asm volatile("" ::: "memory");                                             \
  } while (0)

#define VMC8 asm volatile("s_waitcnt vmcnt(8)" ::: "memory")
#define VMC0 asm volatile("s_waitcnt vmcnt(0)" ::: "memory")

#define PH(READS, STAGES, MQ, NQ, AF, BF, FENCE) do {                          \
    READS;                                                                     \
    STAGES;                                                                    \
    BAR;                                                                       \
    __builtin_amdgcn_s_setprio(1);                                             \
    MFMA_Q(MQ, NQ, AF, BF);                                                    \
    __builtin_amdgcn_s_setprio(0);                                             \
    FENCE;                                                                     \
    BAR;                                                                       \
  } while (0)

// One K-step (BK=64) on buffer BUF; stages tile TS into BUF's slots (if S=1).
#define HALF_STG(BUF, TS, F4)                                                  \
    PH(READ_A(af0, BUF, 0); READ_B(bf0, BUF, 0), , 0, 0, af0, bf0, );          \
    PH(READ_A(af1, BUF, 1), STG_A(BUF, 0, TS), 1, 0, af1, bf0, );              \
    PH(READ_B(bf1, BUF, 1), STG_B(BUF, 0, TS), 1, 1, af1, bf1, );              \
    PH(, STG_A(BUF, 1, TS); STG_B(BUF, 1, TS), 0, 1, af0, bf1, F4);

#define HALF_NOSTG(BUF, F4)                                                    \
    PH(READ_A(af0, BUF, 0); READ_B(bf0, BUF, 0), , 0, 0, af0, bf0, );          \
    PH(READ_A(af1, BUF, 1), , 1, 0, af1, bf0, );                               \
    PH(READ_B(bf1, BUF, 1), , 1, 1, af1, bf1, );                               \
    PH(, , 0, 1, af0, bf1, F4);

#define GEMM8_CORE(A_, LDA_, B_, LDB_, NT_)                                    \
  extern __shared__ char smem[];                                               \
  char* const lsA = smem;                                                      \
  char* const lsB = smem + 65536;                                              \
  const int tid = threadIdx.x;                                                 \
  const int lane = tid & 63;                                                   \
  const int wid = tid >> 6;                                                    \
  const int wr = wid >> 2;                                                     \
  const int wc = wid & 3;                                                      \
  const int fr = lane & 15;                                                    \
  const int kg2 = ((lane >> 4) & 3) << 4;                                      \
  const int lmask = (fr & 6) << 4;                                             \
  f32x4 acc[2][4][2][2];                                                       \
  _Pragma("unroll") for (int a_ = 0; a_ < 2; ++a_)                             \
  _Pragma("unroll") for (int b_ = 0; b_ < 4; ++b_)                             \
  _Pragma("unroll") for (int c_ = 0; c_ < 2; ++c_)                             \
  _Pragma("unroll") for (int d_ = 0; d_ < 2; ++d_)                             \
    acc[a_][b_][c_][d_] = (f32x4){0.f, 0.f, 0.f, 0.f};                         \
  bf16x8 af0[4][2], af1[4][2], bf0[2][2], bf1[2][2];                           \
  const unsigned short* sA[2][2];                                              \
  const unsigned short* sB[2][2];                                              \
  _Pragma("unroll") for (int c_ = 0; c_ < 2; ++c_) {                           \
    int d_ = (tid + 512 * c_) * 16;                                            \
    int p_ = d_ ^ (((d_ >> 8) & 3) << 5);                                      \
    int prow = p_ >> 7, pcol = (p_ & 127) >> 1;                                \
    _Pragma("unroll") for (int s_ = 0; s_ < 2; ++s_) {                         \
      int grA = m0 + ((prow >> 6) & 1) * 128 + s_ * 64 + (prow & 63);          \
      sA[s_][c_] = (A_) + (size_t)grA * (LDA_) + pcol;                         \
      int grB = n0 + (prow >> 5) * 64 + s_ * 32 + (prow & 31);                 \
      sB[s_][c_] = (B_) + (size_t)grB * (LDB_) + pcol;                         \
    }                                                                          \
  }                                                                            \
  /* prologue: tile0 -> buf0 (8 gloads), tile1 -> buf1 (8); drain buf0 */      \
  STG_A(0, 0, 0); STG_B(0, 0, 0); STG_A(0, 1, 0); STG_B(0, 1, 0);              \
  STG_A(1, 0, 1); STG_B(1, 0, 1); STG_A(1, 1, 1); STG_B(1, 1, 1);              \
  VMC8;                                                                        \
  __builtin_amdgcn_s_barrier();                                                \
  asm volatile("" ::: "memory");                                               \
  const int niter = (NT_) / 2;                                                 \
  for (int I = 0; I < niter - 1; ++I) {                                        \
    const int t = 2 * I;                                                       \
    HALF_STG(0, t + 2, VMC8)                                                   \
    HALF_STG(1, t + 3, VMC8)                                                   \
  }                                                                            \
  HALF_NOSTG(0, VMC0)                                                          \
  HALF_NOSTG(1, )

// ---------------- GEMM1: acc = Xb @ Wcat^T, fused SwiGLU epilogue ----------
__global__ __launch_bounds__(512, 2) void gemm_swiglu(
    const unsigned short* __restrict__ Xb,
    const unsigned short* __restrict__ Wcat,
    unsigned short* __restrict__ Act) {
    const int NWG = (TT / 256) * (NCAT / 256);  // 16*112 = 1792
    int lid = (blockIdx.x & 7) * (NWG / 8) + (blockIdx.x >> 3);
    const int m0 = (lid & 15) * 256;   // tm fast: weight panel reused across XCD chunk
    const int n0 = (lid >> 4) * 256;

    GEMM8_CORE(Xb, HH, Wcat, HH, HH / 64)

    const int dm = ((lane >> 4) & 3) * 4;
    const int dn = lane & 15;
#pragma unroll
    for (int mq = 0; mq < 2; ++mq)
#pragma unroll
        for (int i = 0; i < 4; ++i)
#pragma unroll
            for (int nq = 0; nq < 2; ++nq) {
                int rowb = m0 + wr * 128 + mq * 64 + i * 16 + dm;
                int col = (n0 + wc * 64 + nq * 32) / 2 + dn;
                f32x4 g4 = acc[mq][i][nq][0];
                f32x4 u4 = acc[mq][i][nq][1];
#pragma unroll
                for (int r = 0; r < 4; ++r) {
                    float g = g4[r], u = u4[r];
                    float s = g * u / (1.0f + __expf(-g));
                    Act[(size_t)(rowb + r) * FF + col] = f32_to_bf16(s);
                }
            }
}

// ---------------- GEMM2: Out = Act @ W2b^T ----------------------------------
__global__ __launch_bounds__(512, 2) void gemm_down(
    const unsigned short* __restrict__ Act,
    const unsigned short* __restrict__ W2b,
    float* __restrict__ Out) {
    const int NWG = (TT / 256) * (HH / 256);  // 16*16 = 256
    int lid = (blockIdx.x & 7) * (NWG / 8) + (blockIdx.x >> 3);
    const int m0 = (lid & 15) * 256;
    const int n0 = (lid >> 4) * 256;

    GEMM8_CORE(Act, FF, W2b, FF, FF / 64)

    const int dm = ((lane >> 4) & 3) * 4;
    const int dn = lane & 15;
#pragma unroll
    for (int mq = 0; mq < 2; ++mq)
#pragma unroll
        for (int i = 0; i < 4; ++i)
#pragma unroll
            for (int nq = 0; nq < 2; ++nq)
#pragma unroll
                for (int j = 0; j < 2; ++j) {
                    int rowb = m0 + wr * 128 + mq * 64 + i * 16 + dm;
                    int col = n0 + wc * 64 + nq * 32 + j * 16 + dn;
                    f32x4 v = acc[mq][i][nq][j];
#pragma unroll
                    for (int r = 0; r < 4; ++r)
                        Out[(size_t)(rowb + r) * HH + col] = v[r];
                }
}

extern "C" void kernel_launch(void* const* d_in, const int* in_sizes, int n_in,
                              void* d_out, int out_size, void* d_ws, size_t ws_size,
                              hipStream_t stream) {
    const float* x  = (const float*)d_in[0];
    const float* w1 = (const float*)d_in[1];
    const float* v1 = (const float*)d_in[2];
    const float* w2 = (const float*)d_in[3];
    float* out = (float*)d_out;

    unsigned short* xb   = (unsigned short*)d_ws;               // [T][H]
    unsigned short* wcat = xb + (size_t)TT * HH;                // [2F][H]
    unsigned short* w2b  = wcat + (size_t)NCAT * HH;            // [H][F]
    unsigned short* act  = w2b + (size_t)HH * FF;               // [T][F]

    hipFuncSetAttribute((const void*)gemm_swiglu,
                        hipFuncAttributeMaxDynamicSharedMemorySize, 131072);
    hipFuncSetAttribute((const void*)gemm_down,
                        hipFuncAttributeMaxDynamicSharedMemorySize, 131072);

    cvt_lin<<<2048, 256, 0, stream>>>(x, xb, (long)TT * HH / 4);
    cvt_lin<<<2048, 256, 0, stream>>>(w2, w2b, (long)HH * FF / 4);
    cvt_tri<<<(HH / 64) * (FF / 64), 256, 0, stream>>>(w1, wcat, 0);
    cvt_tri<<<(HH / 64) * (FF / 64), 256, 0, stream>>>(v1, wcat, 16);

    gemm_swiglu<<<(TT / 256) * (NCAT / 256), 512, 131072, stream>>>(xb, wcat, act);
    gemm_down<<<(TT / 256) * (HH / 256), 512, 131072, stream>>>(act, w2b, out);
}

// Round 5
// 2349.371 us; speedup vs baseline: 1.0028x; 1.0028x over previous
//
#include <hip/hip_runtime.h>
#include <hip/hip_bf16.h>
#include <stdint.h>

#define TT 4096
#define HH 4096
#define FF 14336
#define NCAT (2 * FF)   // 28672

typedef __attribute__((ext_vector_type(8))) short bf16x8;
typedef __attribute__((ext_vector_type(4))) float f32x4;

__device__ __forceinline__ unsigned short f32_to_bf16(float f) {
    union { float f; unsigned int u; } v; v.f = f;
    unsigned int r = v.u + 0x7FFFu + ((v.u >> 16) & 1u);  // RNE
    return (unsigned short)(r >> 16);
}

#define GLOAD16(g, l)                                                          \
    __builtin_amdgcn_global_load_lds(                                          \
        (const __attribute__((address_space(1))) void*)(g),                    \
        (__attribute__((address_space(3))) void*)(l), 16, 0, 0)

// ---------------- convert fp32 -> bf16, same layout ----------------
__global__ void cvt_lin(const float* __restrict__ in,
                        unsigned short* __restrict__ out, long n4) {
    long stride = (long)gridDim.x * blockDim.x;
    for (long i = (long)blockIdx.x * blockDim.x + threadIdx.x; i < n4; i += stride) {
        float4 v = *(const float4*)(in + i * 4);
        ushort4 o;
        o.x = f32_to_bf16(v.x); o.y = f32_to_bf16(v.y);
        o.z = f32_to_bf16(v.z); o.w = f32_to_bf16(v.w);
        *(ushort4*)(out + i * 4) = o;
    }
}

// ---- convert + transpose + interleave: in [H][F] fp32 -> wcat rows bf16 ----
// f-column f of `in` goes to wcat row ((f>>4)<<5) + (f&15) + off   (off=0 gate, 16 up)
__global__ void cvt_tri(const float* __restrict__ in,
                        unsigned short* __restrict__ out, int off) {
    __shared__ float tile[64][65];
    int bh = blockIdx.x & 63;   // H/64 = 64
    int bf = blockIdx.x >> 6;   // F/64 = 224
    int t = threadIdx.x;
    int r16 = t >> 4;           // 0..15
    int c4 = (t & 15) * 4;      // 0..60
#pragma unroll
    for (int it = 0; it < 4; ++it) {
        int h = r16 + it * 16;
        float4 v = *(const float4*)(in + (size_t)(bh * 64 + h) * FF + bf * 64 + c4);
        tile[h][c4 + 0] = v.x; tile[h][c4 + 1] = v.y;
        tile[h][c4 + 2] = v.z; tile[h][c4 + 3] = v.w;
    }
    __syncthreads();
#pragma unroll
    for (int it = 0; it < 4; ++it) {
        int f = r16 + it * 16;
        int fg = bf * 64 + f;
        int row_out = ((fg >> 4) << 5) + (fg & 15) + off;
        ushort4 o;
        o.x = f32_to_bf16(tile[c4 + 0][f]);
        o.y = f32_to_bf16(tile[c4 + 1][f]);
        o.z = f32_to_bf16(tile[c4 + 2][f]);
        o.w = f32_to_bf16(tile[c4 + 3][f]);
        *(ushort4*)(out + (size_t)row_out * HH + bh * 64 + c4) = o;
    }
}

// =================== 8-phase 256x256 GEMM core (BK=64, 8 waves) ============
// LDS: lsA[2buf][2mhalf][128][64]b16 (16KiB slots), lsB same. 128 KiB total.
// Swizzle: byte ^= ((row&6)<<4)  (applied to gload SOURCE and ds_read; LDS linear).
// Register-held fragments: each LDS fragment read exactly ONCE per K-step.
// Snake quadrant order: (m0n0)->(m1n0)->(m1n1)->(m0n1).
// Stage map (slot dead >=1 phase before overwrite): ph2<-A0, ph3<-B0, ph4<-A1+B1.
// Fence: vmcnt(8) at ph4/ph8 only (8 gloads = one K-step's stages stay in flight).
// NOTE __launch_bounds__(512, 1): with (512,2) the allocator capped VGPRs at 128
// (2nd arg acted as min-BLOCKS/CU -> 4 waves/EU) and spilled the 96 fragment
// regs to scratch (round-4 regression: WRITE_SIZE +75MB, MfmaUtil 46->26).

#define STG_A(BUF, SLOT, TILE) do {                                            \
    char* d_ = lsA + (((BUF)*2 + (SLOT)) << 14) + tid * 16;                    \
    GLOAD16(sA[SLOT][0] + (size_t)(TILE) * 64, d_);                            \
    GLOAD16(sA[SLOT][1] + (size_t)(TILE) * 64, d_ + 8192);                     \
  } while (0)

#define STG_B(BUF, SLOT, TILE) do {                                            \
    char* d_ = lsB + (((BUF)*2 + (SLOT)) << 14) + tid * 16;                    \
    GLOAD16(sB[SLOT][0] + (size_t)(TILE) * 64, d_);                            \
    GLOAD16(sB[SLOT][1] + (size_t)(TILE) * 64, d_ + 8192);                     \
  } while (0)

#define READ_A(DST, BUF, MQ) do {                                              \
    const char* pA_ = lsA + (((BUF)*2 + (MQ)) << 14);                          \
    _Pragma("unroll") for (int i_ = 0; i_ < 4; ++i_)                           \
    _Pragma("unroll") for (int k_ = 0; k_ < 2; ++k_)                           \
      DST[i_][k_] = *(const bf16x8*)(pA_ + ((((wr*64 + i_*16 + fr) << 7) + k_*64 + kg2) ^ lmask)); \
  } while (0)

#define READ_B(DST, BUF, NQ) do {                                              \
    const char* pB_ = lsB + (((BUF)*2 + (NQ)) << 14);                          \
    _Pragma("unroll") for (int j_ = 0; j_ < 2; ++j_)                           \
    _Pragma("unroll") for (int k_ = 0; k_ < 2; ++k_)                           \
      DST[j_][k_] = *(const bf16x8*)(pB_ + ((((wc*32 + j_*16 + fr) << 7) + k_*64 + kg2) ^ lmask)); \
  } while (0)

#define MFMA_Q(MQ, NQ, AF, BF)                                                 \
    _Pragma("unroll") for (int i_ = 0; i_ < 4; ++i_)                           \
    _Pragma("unroll") for (int j_ = 0; j_ < 2; ++j_)                           \
    _Pragma("unroll") for (int k_ = 0; k_ < 2; ++k_)                           \
      acc[MQ][i_][NQ][j_] = __builtin_amdgcn_mfma_f32_16x16x32_bf16(           \
          AF[i_][k_], BF[j_][k_], acc[MQ][i_][NQ][j_], 0, 0, 0)

#define BAR do {                                                               \
    asm volatile("" ::: "memory");                                             \
    __builtin_amdgcn_s_barrier();                                              \
    asm volatile("" ::: "memory");                                             \
  } while (0)

#define VMC8 asm volatile("s_waitcnt vmcnt(8)" ::: "memory")
#define VMC0 asm volatile("s_waitcnt vmcnt(0)" ::: "memory")

#define PH(READS, STAGES, MQ, NQ, AF, BF, FENCE) do {                          \
    READS;                                                                     \
    STAGES;                                                                    \
    BAR;                                                                       \
    __builtin_amdgcn_s_setprio(1);                                             \
    MFMA_Q(MQ, NQ, AF, BF);                                                    \
    __builtin_amdgcn_s_setprio(0);                                             \
    FENCE;                                                                     \
    BAR;                                                                       \
  } while (0)

// One K-step (BK=64) on buffer BUF; stages tile TS into BUF's slots (if S=1).
#define HALF_STG(BUF, TS, F4)                                                  \
    PH(READ_A(af0, BUF, 0); READ_B(bf0, BUF, 0), , 0, 0, af0, bf0, );          \
    PH(READ_A(af1, BUF, 1), STG_A(BUF, 0, TS), 1, 0, af1, bf0, );              \
    PH(READ_B(bf1, BUF, 1), STG_B(BUF, 0, TS), 1, 1, af1, bf1, );              \
    PH(, STG_A(BUF, 1, TS); STG_B(BUF, 1, TS), 0, 1, af0, bf1, F4);

#define HALF_NOSTG(BUF, F4)                                                    \
    PH(READ_A(af0, BUF, 0); READ_B(bf0, BUF, 0), , 0, 0, af0, bf0, );          \
    PH(READ_A(af1, BUF, 1), , 1, 0, af1, bf0, );                               \
    PH(READ_B(bf1, BUF, 1), , 1, 1, af1, bf1, );                               \
    PH(, , 0, 1, af0, bf1, F4);

#define GEMM8_CORE(A_, LDA_, B_, LDB_, NT_)                                    \
  extern __shared__ char smem[];                                               \
  char* const lsA = smem;                                                      \
  char* const lsB = smem + 65536;                                              \
  const int tid = threadIdx.x;                                                 \
  const int lane = tid & 63;                                                   \
  const int wid = tid >> 6;                                                    \
  const int wr = wid >> 2;                                                     \
  const int wc = wid & 3;                                                      \
  const int fr = lane & 15;                                                    \
  const int kg2 = ((lane >> 4) & 3) << 4;                                      \
  const int lmask = (fr & 6) << 4;                                             \
  f32x4 acc[2][4][2][2];                                                       \
  _Pragma("unroll") for (int a_ = 0; a_ < 2; ++a_)                             \
  _Pragma("unroll") for (int b_ = 0; b_ < 4; ++b_)                             \
  _Pragma("unroll") for (int c_ = 0; c_ < 2; ++c_)                             \
  _Pragma("unroll") for (int d_ = 0; d_ < 2; ++d_)                             \
    acc[a_][b_][c_][d_] = (f32x4){0.f, 0.f, 0.f, 0.f};                         \
  bf16x8 af0[4][2], af1[4][2], bf0[2][2], bf1[2][2];                           \
  const unsigned short* sA[2][2];                                              \
  const unsigned short* sB[2][2];                                              \
  _Pragma("unroll") for (int c_ = 0; c_ < 2; ++c_) {                           \
    int d_ = (tid + 512 * c_) * 16;                                            \
    int p_ = d_ ^ (((d_ >> 8) & 3) << 5);                                      \
    int prow = p_ >> 7, pcol = (p_ & 127) >> 1;                                \
    _Pragma("unroll") for (int s_ = 0; s_ < 2; ++s_) {                         \
      int grA = m0 + ((prow >> 6) & 1) * 128 + s_ * 64 + (prow & 63);          \
      sA[s_][c_] = (A_) + (size_t)grA * (LDA_) + pcol;                         \
      int grB = n0 + (prow >> 5) * 64 + s_ * 32 + (prow & 31);                 \
      sB[s_][c_] = (B_) + (size_t)grB * (LDB_) + pcol;                         \
    }                                                                          \
  }                                                                            \
  /* prologue: tile0 -> buf0 (8 gloads), tile1 -> buf1 (8); drain buf0 */      \
  STG_A(0, 0, 0); STG_B(0, 0, 0); STG_A(0, 1, 0); STG_B(0, 1, 0);              \
  STG_A(1, 0, 1); STG_B(1, 0, 1); STG_A(1, 1, 1); STG_B(1, 1, 1);              \
  VMC8;                                                                        \
  __builtin_amdgcn_s_barrier();                                                \
  asm volatile("" ::: "memory");                                               \
  const int niter = (NT_) / 2;                                                 \
  for (int I = 0; I < niter - 1; ++I) {                                        \
    const int t = 2 * I;                                                       \
    HALF_STG(0, t + 2, VMC8)                                                   \
    HALF_STG(1, t + 3, VMC8)                                                   \
  }                                                                            \
  HALF_NOSTG(0, VMC0)                                                          \
  HALF_NOSTG(1, )

// ---------------- GEMM1: acc = Xb @ Wcat^T, fused SwiGLU epilogue ----------
__global__ __launch_bounds__(512, 1) void gemm_swiglu(
    const unsigned short* __restrict__ Xb,
    const unsigned short* __restrict__ Wcat,
    unsigned short* __restrict__ Act) {
    const int NWG = (TT / 256) * (NCAT / 256);  // 16*112 = 1792
    int lid = (blockIdx.x & 7) * (NWG / 8) + (blockIdx.x >> 3);
    const int m0 = (lid & 15) * 256;   // tm fast: weight panel reused across XCD chunk
    const int n0 = (lid >> 4) * 256;

    GEMM8_CORE(Xb, HH, Wcat, HH, HH / 64)

    const int dm = ((lane >> 4) & 3) * 4;
    const int dn = lane & 15;
#pragma unroll
    for (int mq = 0; mq < 2; ++mq)
#pragma unroll
        for (int i = 0; i < 4; ++i)
#pragma unroll
            for (int nq = 0; nq < 2; ++nq) {
                int rowb = m0 + wr * 128 + mq * 64 + i * 16 + dm;
                int col = (n0 + wc * 64 + nq * 32) / 2 + dn;
                f32x4 g4 = acc[mq][i][nq][0];
                f32x4 u4 = acc[mq][i][nq][1];
#pragma unroll
                for (int r = 0; r < 4; ++r) {
                    float g = g4[r], u = u4[r];
                    float s = g * u / (1.0f + __expf(-g));
                    Act[(size_t)(rowb + r) * FF + col] = f32_to_bf16(s);
                }
            }
}

// ---------------- GEMM2: Out = Act @ W2b^T ----------------------------------
__global__ __launch_bounds__(512, 1) void gemm_down(
    const unsigned short* __restrict__ Act,
    const unsigned short* __restrict__ W2b,
    float* __restrict__ Out) {
    const int NWG = (TT / 256) * (HH / 256);  // 16*16 = 256
    int lid = (blockIdx.x & 7) * (NWG / 8) + (blockIdx.x >> 3);
    const int m0 = (lid & 15) * 256;
    const int n0 = (lid >> 4) * 256;

    GEMM8_CORE(Act, FF, W2b, FF, FF / 64)

    const int dm = ((lane >> 4) & 3) * 4;
    const int dn = lane & 15;
#pragma unroll
    for (int mq = 0; mq < 2; ++mq)
#pragma unroll
        for (int i = 0; i < 4; ++i)
#pragma unroll
            for (int nq = 0; nq < 2; ++nq)
#pragma unroll
                for (int j = 0; j < 2; ++j) {
                    int rowb = m0 + wr * 128 + mq * 64 + i * 16 + dm;
                    int col = n0 + wc * 64 + nq * 32 + j * 16 + dn;
                    f32x4 v = acc[mq][i][nq][j];
#pragma unroll
                    for (int r = 0; r < 4; ++r)
                        Out[(size_t)(rowb + r) * HH + col] = v[r];
                }
}

extern "C" void kernel_launch(void* const* d_in, const int* in_sizes, int n_in,
                              void* d_out, int out_size, void* d_ws, size_t ws_size,
                              hipStream_t stream) {
    const float* x  = (const float*)d_in[0];
    const float* w1 = (const float*)d_in[1];
    const float* v1 = (const float*)d_in[2];
    const float* w2 = (const float*)d_in[3];
    float* out = (float*)d_out;

    unsigned short* xb   = (unsigned short*)d_ws;               // [T][H]
    unsigned short* wcat = xb + (size_t)TT * HH;                // [2F][H]
    unsigned short* w2b  = wcat + (size_t)NCAT * HH;            // [H][F]
    unsigned short* act  = w2b + (size_t)HH * FF;               // [T][F]

    hipFuncSetAttribute((const void*)gemm_swiglu,
                        hipFuncAttributeMaxDynamicSharedMemorySize, 131072);
    hipFuncSetAttribute((const void*)gemm_down,
                        hipFuncAttributeMaxDynamicSharedMemorySize, 131072);

    cvt_lin<<<2048, 256, 0, stream>>>(x, xb, (long)TT * HH / 4);
    cvt_lin<<<2048, 256, 0, stream>>>(w2, w2b, (long)HH * FF / 4);
    cvt_tri<<<(HH / 64) * (FF / 64), 256, 0, stream>>>(w1, wcat, 0);
    cvt_tri<<<(HH / 64) * (FF / 64), 256, 0, stream>>>(v1, wcat, 16);

    gemm_swiglu<<<(TT / 256) * (NCAT / 256), 512, 131072, stream>>>(xb, wcat, act);
    gemm_down<<<(TT / 256) * (HH / 256), 512, 131072, stream>>>(act, w2b, out);
}

// Round 6
// 1586.895 us; speedup vs baseline: 1.4846x; 1.4805x over previous
//
#include <hip/hip_runtime.h>
#include <hip/hip_bf16.h>
#include <stdint.h>

#define TT 4096
#define HH 4096
#define FF 14336
#define NCAT (2 * FF)   // 28672

typedef __attribute__((ext_vector_type(8))) short bf16x8;
typedef __attribute__((ext_vector_type(4))) float f32x4;

__device__ __forceinline__ unsigned short f32_to_bf16(float f) {
    union { float f; unsigned int u; } v; v.f = f;
    unsigned int r = v.u + 0x7FFFu + ((v.u >> 16) & 1u);  // RNE
    return (unsigned short)(r >> 16);
}

#define GLOAD16(g, l)                                                          \
    __builtin_amdgcn_global_load_lds(                                          \
        (const __attribute__((address_space(1))) void*)(g),                    \
        (__attribute__((address_space(3))) void*)(l), 16, 0, 0)

// ---------------- convert fp32 -> bf16, same layout ----------------
__global__ void cvt_lin(const float* __restrict__ in,
                        unsigned short* __restrict__ out, long n4) {
    long stride = (long)gridDim.x * blockDim.x;
    for (long i = (long)blockIdx.x * blockDim.x + threadIdx.x; i < n4; i += stride) {
        float4 v = *(const float4*)(in + i * 4);
        ushort4 o;
        o.x = f32_to_bf16(v.x); o.y = f32_to_bf16(v.y);
        o.z = f32_to_bf16(v.z); o.w = f32_to_bf16(v.w);
        *(ushort4*)(out + i * 4) = o;
    }
}

// ---- convert + transpose + interleave: in [H][F] fp32 -> wcat rows bf16 ----
// f-column f of `in` goes to wcat row ((f>>4)<<5) + (f&15) + off   (off=0 gate, 16 up)
__global__ void cvt_tri(const float* __restrict__ in,
                        unsigned short* __restrict__ out, int off) {
    __shared__ float tile[64][65];
    int bh = blockIdx.x & 63;   // H/64 = 64
    int bf = blockIdx.x >> 6;   // F/64 = 224
    int t = threadIdx.x;
    int r16 = t >> 4;           // 0..15
    int c4 = (t & 15) * 4;      // 0..60
#pragma unroll
    for (int it = 0; it < 4; ++it) {
        int h = r16 + it * 16;
        float4 v = *(const float4*)(in + (size_t)(bh * 64 + h) * FF + bf * 64 + c4);
        tile[h][c4 + 0] = v.x; tile[h][c4 + 1] = v.y;
        tile[h][c4 + 2] = v.z; tile[h][c4 + 3] = v.w;
    }
    __syncthreads();
#pragma unroll
    for (int it = 0; it < 4; ++it) {
        int f = r16 + it * 16;
        int fg = bf * 64 + f;
        int row_out = ((fg >> 4) << 5) + (fg & 15) + off;
        ushort4 o;
        o.x = f32_to_bf16(tile[c4 + 0][f]);
        o.y = f32_to_bf16(tile[c4 + 1][f]);
        o.z = f32_to_bf16(tile[c4 + 2][f]);
        o.w = f32_to_bf16(tile[c4 + 3][f]);
        *(ushort4*)(out + (size_t)row_out * HH + bh * 64 + c4) = o;
    }
}

// =================== 8-phase 256x256 GEMM core (BK=64, 8 waves) ============
// LDS: lsA[2buf][2mhalf][128][64]b16 (16KiB slots), lsB same. 128 KiB total.
// Swizzle: byte ^= ((row&6)<<4)  (applied to gload SOURCE and ds_read; LDS linear).
// Register-held fragments, each LDS fragment read exactly ONCE per K-step.
// Snake order (m0n0)->(m0n1)->(m1n1)->(m1n0): B operand repeated at the ends,
// so live frags = ONE A buffer (32 VGPR, overwritten in place at ph3) + two B
// buffers (2x16) = 64 VGPRs  (round-4's A-repeating snake needed 96 -> spill).
// Reads/phase: 12 / 4 / 8 / 0.  Stage map (slot dead >=1 barrier earlier):
//   ph2 <- A0+B0 (4 gloads), ph3 <- B1 (2), ph4 <- A1 (2).
// Fence vmcnt(8) at ph4 only: this K-step's 8 stages stay in flight; the
// previous K-step's 8 (for the OTHER buffer, read next K-step) have landed.
// amdgpu_waves_per_eu(1,2): real occupancy is LDS-capped at 2 waves/EU
// (dynamic 128KiB invisible to the allocator) -> allow the 256-VGPR budget;
// without it the heuristic pins 128 arch VGPRs and spills (rounds 4-5:
// WRITE_SIZE +75MB, MfmaUtil 46->26).

#define STG_A(BUF, SLOT, TILE) do {                                            \
    char* d_ = lsA + (((BUF)*2 + (SLOT)) << 14) + tid * 16;                    \
    GLOAD16(sA[SLOT][0] + (size_t)(TILE) * 64, d_);                            \
    GLOAD16(sA[SLOT][1] + (size_t)(TILE) * 64, d_ + 8192);                     \
  } while (0)

#define STG_B(BUF, SLOT, TILE) do {                                            \
    char* d_ = lsB + (((BUF)*2 + (SLOT)) << 14) + tid * 16;                    \
    GLOAD16(sB[SLOT][0] + (size_t)(TILE) * 64, d_);                            \
    GLOAD16(sB[SLOT][1] + (size_t)(TILE) * 64, d_ + 8192);                     \
  } while (0)

#define READ_A(DST, BUF, MQ) do {                                              \
    const char* pA_ = lsA + (((BUF)*2 + (MQ)) << 14);                          \
    _Pragma("unroll") for (int i_ = 0; i_ < 4; ++i_)                           \
    _Pragma("unroll") for (int k_ = 0; k_ < 2; ++k_)                           \
      DST[i_][k_] = *(const bf16x8*)(pA_ + ((((wr*64 + i_*16 + fr) << 7) + k_*64 + kg2) ^ lmask)); \
  } while (0)

#define READ_B(DST, BUF, NQ) do {                                              \
    const char* pB_ = lsB + (((BUF)*2 + (NQ)) << 14);                          \
    _Pragma("unroll") for (int j_ = 0; j_ < 2; ++j_)                           \
    _Pragma("unroll") for (int k_ = 0; k_ < 2; ++k_)                           \
      DST[j_][k_] = *(const bf16x8*)(pB_ + ((((wc*32 + j_*16 + fr) << 7) + k_*64 + kg2) ^ lmask)); \
  } while (0)

#define MFMA_Q(MQ, NQ, AF, BF)                                                 \
    _Pragma("unroll") for (int i_ = 0; i_ < 4; ++i_)                           \
    _Pragma("unroll") for (int j_ = 0; j_ < 2; ++j_)                           \
    _Pragma("unroll") for (int k_ = 0; k_ < 2; ++k_)                           \
      acc[MQ][i_][NQ][j_] = __builtin_amdgcn_mfma_f32_16x16x32_bf16(           \
          AF[i_][k_], BF[j_][k_], acc[MQ][i_][NQ][j_], 0, 0, 0)

#define BAR do {                                                               \
    asm volatile("" ::: "memory");                                             \
    __builtin_amdgcn_s_barrier();                                              \
    asm volatile("" ::: "memory");                                             \
  } while (0)

#define VMC8 asm volatile("s_waitcnt vmcnt(8)" ::: "memory")
#define VMC0 asm volatile("s_waitcnt vmcnt(0)" ::: "memory")

#define PH(READS, STAGES, MQ, NQ, AF, BF, FENCE) do {                          \
    READS;                                                                     \
    STAGES;                                                                    \
    BAR;                                                                       \
    __builtin_amdgcn_s_setprio(1);                                             \
    MFMA_Q(MQ, NQ, AF, BF);                                                    \
    __builtin_amdgcn_s_setprio(0);                                             \
    FENCE;                                                                     \
    BAR;                                                                       \
  } while (0)

// One K-step (BK=64) on buffer BUF; stages tile TS into BUF's just-freed slots.
#define HALF_STG(BUF, TS, F4)                                                  \
    PH(READ_A(af, BUF, 0); READ_B(bf0, BUF, 0), , 0, 0, af, bf0, );            \
    PH(READ_B(bf1, BUF, 1), STG_A(BUF, 0, TS); STG_B(BUF, 0, TS), 0, 1, af, bf1, ); \
    PH(READ_A(af, BUF, 1), STG_B(BUF, 1, TS), 1, 1, af, bf1, );                \
    PH(, STG_A(BUF, 1, TS), 1, 0, af, bf0, F4);

#define HALF_NOSTG(BUF, F4)                                                    \
    PH(READ_A(af, BUF, 0); READ_B(bf0, BUF, 0), , 0, 0, af, bf0, );            \
    PH(READ_B(bf1, BUF, 1), , 0, 1, af, bf1, );                                \
    PH(READ_A(af, BUF, 1), , 1, 1, af, bf1, );                                 \
    PH(, , 1, 0, af, bf0, F4);

#define GEMM8_CORE(A_, LDA_, B_, LDB_, NT_)                                    \
  extern __shared__ char smem[];                                               \
  char* const lsA = smem;                                                      \
  char* const lsB = smem + 65536;                                              \
  const int tid = threadIdx.x;                                                 \
  const int lane = tid & 63;                                                   \
  const int wid = tid >> 6;                                                    \
  const int wr = wid >> 2;                                                     \
  const int wc = wid & 3;                                                      \
  const int fr = lane & 15;                                                    \
  const int kg2 = ((lane >> 4) & 3) << 4;                                      \
  const int lmask = (fr & 6) << 4;                                             \
  f32x4 acc[2][4][2][2];                                                       \
  _Pragma("unroll") for (int a_ = 0; a_ < 2; ++a_)                             \
  _Pragma("unroll") for (int b_ = 0; b_ < 4; ++b_)                             \
  _Pragma("unroll") for (int c_ = 0; c_ < 2; ++c_)                             \
  _Pragma("unroll") for (int d_ = 0; d_ < 2; ++d_)                             \
    acc[a_][b_][c_][d_] = (f32x4){0.f, 0.f, 0.f, 0.f};                         \
  bf16x8 af[4][2], bf0[2][2], bf1[2][2];                                       \
  const unsigned short* sA[2][2];                                              \
  const unsigned short* sB[2][2];                                              \
  _Pragma("unroll") for (int c_ = 0; c_ < 2; ++c_) {                           \
    int d_ = (tid + 512 * c_) * 16;                                            \
    int p_ = d_ ^ (((d_ >> 8) & 3) << 5);                                      \
    int prow = p_ >> 7, pcol = (p_ & 127) >> 1;                                \
    _Pragma("unroll") for (int s_ = 0; s_ < 2; ++s_) {                         \
      int grA = m0 + ((prow >> 6) & 1) * 128 + s_ * 64 + (prow & 63);          \
      sA[s_][c_] = (A_) + (size_t)grA * (LDA_) + pcol;                         \
      int grB = n0 + (prow >> 5) * 64 + s_ * 32 + (prow & 31);                 \
      sB[s_][c_] = (B_) + (size_t)grB * (LDB_) + pcol;                         \
    }                                                                          \
  }                                                                            \
  /* prologue: tile0 -> buf0 (8 gloads), tile1 -> buf1 (8); drain buf0 */      \
  STG_A(0, 0, 0); STG_B(0, 0, 0); STG_A(0, 1, 0); STG_B(0, 1, 0);              \
  STG_A(1, 0, 1); STG_B(1, 0, 1); STG_A(1, 1, 1); STG_B(1, 1, 1);              \
  VMC8;                                                                        \
  __builtin_amdgcn_s_barrier();                                                \
  asm volatile("" ::: "memory");                                               \
  const int niter = (NT_) / 2;                                                 \
  for (int I = 0; I < niter - 1; ++I) {                                        \
    const int t = 2 * I;                                                       \
    HALF_STG(0, t + 2, VMC8)                                                   \
    HALF_STG(1, t + 3, VMC8)                                                   \
  }                                                                            \
  HALF_NOSTG(0, VMC0)                                                          \
  HALF_NOSTG(1, )

// ---------------- GEMM1: acc = Xb @ Wcat^T, fused SwiGLU epilogue ----------
__global__ __launch_bounds__(512)
__attribute__((amdgpu_waves_per_eu(1, 2))) void gemm_swiglu(
    const unsigned short* __restrict__ Xb,
    const unsigned short* __restrict__ Wcat,
    unsigned short* __restrict__ Act) {
    const int NWG = (TT / 256) * (NCAT / 256);  // 16*112 = 1792
    int lid = (blockIdx.x & 7) * (NWG / 8) + (blockIdx.x >> 3);
    const int m0 = (lid & 15) * 256;   // tm fast: weight panel reused across XCD chunk
    const int n0 = (lid >> 4) * 256;

    GEMM8_CORE(Xb, HH, Wcat, HH, HH / 64)

    const int dm = ((lane >> 4) & 3) * 4;
    const int dn = lane & 15;
#pragma unroll
    for (int mq = 0; mq < 2; ++mq)
#pragma unroll
        for (int i = 0; i < 4; ++i)
#pragma unroll
            for (int nq = 0; nq < 2; ++nq) {
                int rowb = m0 + wr * 128 + mq * 64 + i * 16 + dm;
                int col = (n0 + wc * 64 + nq * 32) / 2 + dn;
                f32x4 g4 = acc[mq][i][nq][0];
                f32x4 u4 = acc[mq][i][nq][1];
#pragma unroll
                for (int r = 0; r < 4; ++r) {
                    float g = g4[r], u = u4[r];
                    float s = g * u / (1.0f + __expf(-g));
                    Act[(size_t)(rowb + r) * FF + col] = f32_to_bf16(s);
                }
            }
}

// ---------------- GEMM2: Out = Act @ W2b^T ----------------------------------
__global__ __launch_bounds__(512)
__attribute__((amdgpu_waves_per_eu(1, 2))) void gemm_down(
    const unsigned short* __restrict__ Act,
    const unsigned short* __restrict__ W2b,
    float* __restrict__ Out) {
    const int NWG = (TT / 256) * (HH / 256);  // 16*16 = 256
    int lid = (blockIdx.x & 7) * (NWG / 8) + (blockIdx.x >> 3);
    const int m0 = (lid & 15) * 256;
    const int n0 = (lid >> 4) * 256;

    GEMM8_CORE(Act, FF, W2b, FF, FF / 64)

    const int dm = ((lane >> 4) & 3) * 4;
    const int dn = lane & 15;
#pragma unroll
    for (int mq = 0; mq < 2; ++mq)
#pragma unroll
        for (int i = 0; i < 4; ++i)
#pragma unroll
            for (int nq = 0; nq < 2; ++nq)
#pragma unroll
                for (int j = 0; j < 2; ++j) {
                    int rowb = m0 + wr * 128 + mq * 64 + i * 16 + dm;
                    int col = n0 + wc * 64 + nq * 32 + j * 16 + dn;
                    f32x4 v = acc[mq][i][nq][j];
#pragma unroll
                    for (int r = 0; r < 4; ++r)
                        Out[(size_t)(rowb + r) * HH + col] = v[r];
                }
}

extern "C" void kernel_launch(void* const* d_in, const int* in_sizes, int n_in,
                              void* d_out, int out_size, void* d_ws, size_t ws_size,
                              hipStream_t stream) {
    const float* x  = (const float*)d_in[0];
    const float* w1 = (const float*)d_in[1];
    const float* v1 = (const float*)d_in[2];
    const float* w2 = (const float*)d_in[3];
    float* out = (float*)d_out;

    unsigned short* xb   = (unsigned short*)d_ws;               // [T][H]
    unsigned short* wcat = xb + (size_t)TT * HH;                // [2F][H]
    unsigned short* w2b  = wcat + (size_t)NCAT * HH;            // [H][F]
    unsigned short* act  = w2b + (size_t)HH * FF;               // [T][F]

    hipFuncSetAttribute((const void*)gemm_swiglu,
                        hipFuncAttributeMaxDynamicSharedMemorySize, 131072);
    hipFuncSetAttribute((const void*)gemm_down,
                        hipFuncAttributeMaxDynamicSharedMemorySize, 131072);

    cvt_lin<<<2048, 256, 0, stream>>>(x, xb, (long)TT * HH / 4);
    cvt_lin<<<2048, 256, 0, stream>>>(w2, w2b, (long)HH * FF / 4);
    cvt_tri<<<(HH / 64) * (FF / 64), 256, 0, stream>>>(w1, wcat, 0);
    cvt_tri<<<(HH / 64) * (FF / 64), 256, 0, stream>>>(v1, wcat, 16);

    gemm_swiglu<<<(TT / 256) * (NCAT / 256), 512, 131072, stream>>>(xb, wcat, act);
    gemm_down<<<(TT / 256) * (HH / 256), 512, 131072, stream>>>(act, w2b, out);
}

// Round 7
// 1373.154 us; speedup vs baseline: 1.7156x; 1.1557x over previous
//
#include <hip/hip_runtime.h>
#include <hip/hip_bf16.h>
#include <stdint.h>

#define TT 4096
#define HH 4096
#define FF 14336
#define NCAT (2 * FF)   // 28672

typedef __attribute__((ext_vector_type(8))) short bf16x8;
typedef __attribute__((ext_vector_type(4))) float f32x4;

__device__ __forceinline__ unsigned short f32_to_bf16(float f) {
    union { float f; unsigned int u; } v; v.f = f;
    unsigned int r = v.u + 0x7FFFu + ((v.u >> 16) & 1u);  // RNE
    return (unsigned short)(r >> 16);
}

#define GLOAD16(g, l)                                                          \
    __builtin_amdgcn_global_load_lds(                                          \
        (const __attribute__((address_space(1))) void*)(g),                    \
        (__attribute__((address_space(3))) void*)(l), 16, 0, 0)

// ---------------- convert fp32 -> bf16, same layout ----------------
__global__ void cvt_lin(const float* __restrict__ in,
                        unsigned short* __restrict__ out, long n4) {
    long stride = (long)gridDim.x * blockDim.x;
    for (long i = (long)blockIdx.x * blockDim.x + threadIdx.x; i < n4; i += stride) {
        float4 v = *(const float4*)(in + i * 4);
        ushort4 o;
        o.x = f32_to_bf16(v.x); o.y = f32_to_bf16(v.y);
        o.z = f32_to_bf16(v.z); o.w = f32_to_bf16(v.w);
        *(ushort4*)(out + i * 4) = o;
    }
}

// ---- convert + transpose + interleave: in [H][F] fp32 -> wcat rows bf16 ----
// f-column f of `in` goes to wcat row ((f>>4)<<5) + (f&15) + off   (off=0 gate, 16 up)
__global__ void cvt_tri(const float* __restrict__ in,
                        unsigned short* __restrict__ out, int off) {
    __shared__ float tile[64][65];
    int bh = blockIdx.x & 63;   // H/64 = 64
    int bf = blockIdx.x >> 6;   // F/64 = 224
    int t = threadIdx.x;
    int r16 = t >> 4;           // 0..15
    int c4 = (t & 15) * 4;      // 0..60
#pragma unroll
    for (int it = 0; it < 4; ++it) {
        int h = r16 + it * 16;
        float4 v = *(const float4*)(in + (size_t)(bh * 64 + h) * FF + bf * 64 + c4);
        tile[h][c4 + 0] = v.x; tile[h][c4 + 1] = v.y;
        tile[h][c4 + 2] = v.z; tile[h][c4 + 3] = v.w;
    }
    __syncthreads();
#pragma unroll
    for (int it = 0; it < 4; ++it) {
        int f = r16 + it * 16;
        int fg = bf * 64 + f;
        int row_out = ((fg >> 4) << 5) + (fg & 15) + off;
        ushort4 o;
        o.x = f32_to_bf16(tile[c4 + 0][f]);
        o.y = f32_to_bf16(tile[c4 + 1][f]);
        o.z = f32_to_bf16(tile[c4 + 2][f]);
        o.w = f32_to_bf16(tile[c4 + 3][f]);
        *(ushort4*)(out + (size_t)row_out * HH + bh * 64 + c4) = o;
    }
}

// =================== 8-phase 256x256 GEMM core (BK=64, 8 waves) ============
// LDS: lsA[2buf][2mhalf][128][64]b16 (16KiB slots), lsB same. 128 KiB total.
// Swizzle: byte ^= ((row&6)<<4)  (applied to gload SOURCE and ds_read; LDS linear).
// Register budget model (rounds 4-6): acc = 128 AGPRs; 2 waves/EU -> 256
// unified budget -> arch-VGPR hard cap 128. So held fragments + addressing
// must fit 128. This version holds only af (32, overwritten in place) +
// bf1 (16, one barrier) -> ~110 arch VGPRs, no spill.
// Snake order (m0n0)->(m0n1)->(m1n1)->(m1n0); B0 re-read from LDS at ph4.
// ds_reads per phase: 12 / 4 / 8 / 4 = 28 per K-step (48 in round 3).
// Stage map (issue always >=1 barrier after the slot's last read):
//   ph1 -> OTHER.B0 tile(t+1)   (B0 last read: prev K-step ph4)
//   ph2 -> OWN.A0  tile(t+2)    (A0 last LDS read: ph1)
//   ph4 -> OWN.B1 + OWN.A1 t+2  (last reads: ph3)
// Fence vmcnt(6) at ph4 only: youngest load that must land before the next
// K-step's reads is OTHER.B0 (issued ph1); loads after it = A0(2)+B1(2)+A1(2).
// Prologue: buf0 all (8) + buf1 {A0,B1,A1} (6), vmcnt(6); buf1.B0 staged at
// K-step0.ph1. Tail: T1 stages last B0 then drains vmcnt(0); T2 pure compute.

#define STG_A(BUF, SLOT, TILE) do {                                            \
    char* d_ = lsA + (((BUF)*2 + (SLOT)) << 14) + tid * 16;                    \
    GLOAD16(sA[SLOT][0] + (size_t)(TILE) * 64, d_);                            \
    GLOAD16(sA[SLOT][1] + (size_t)(TILE) * 64, d_ + 8192);                     \
  } while (0)

#define STG_B(BUF, SLOT, TILE) do {                                            \
    char* d_ = lsB + (((BUF)*2 + (SLOT)) << 14) + tid * 16;                    \
    GLOAD16(sB[SLOT][0] + (size_t)(TILE) * 64, d_);                            \
    GLOAD16(sB[SLOT][1] + (size_t)(TILE) * 64, d_ + 8192);                     \
  } while (0)

#define READ_A(DST, BUF, MQ) do {                                              \
    const char* pA_ = lsA + (((BUF)*2 + (MQ)) << 14);                          \
    _Pragma("unroll") for (int i_ = 0; i_ < 4; ++i_)                           \
    _Pragma("unroll") for (int k_ = 0; k_ < 2; ++k_)                           \
      DST[i_][k_] = *(const bf16x8*)(pA_ + ((((wr*64 + i_*16 + fr) << 7) + k_*64 + kg2) ^ lmask)); \
  } while (0)

#define READ_B(DST, BUF, NQ) do {                                              \
    const char* pB_ = lsB + (((BUF)*2 + (NQ)) << 14);                          \
    _Pragma("unroll") for (int j_ = 0; j_ < 2; ++j_)                           \
    _Pragma("unroll") for (int k_ = 0; k_ < 2; ++k_)                           \
      DST[j_][k_] = *(const bf16x8*)(pB_ + ((((wc*32 + j_*16 + fr) << 7) + k_*64 + kg2) ^ lmask)); \
  } while (0)

#define MFMA_Q(MQ, NQ, AF, BF)                                                 \
    _Pragma("unroll") for (int i_ = 0; i_ < 4; ++i_)                           \
    _Pragma("unroll") for (int j_ = 0; j_ < 2; ++j_)                           \
    _Pragma("unroll") for (int k_ = 0; k_ < 2; ++k_)                           \
      acc[MQ][i_][NQ][j_] = __builtin_amdgcn_mfma_f32_16x16x32_bf16(           \
          AF[i_][k_], BF[j_][k_], acc[MQ][i_][NQ][j_], 0, 0, 0)

#define BAR do {                                                               \
    asm volatile("" ::: "memory");                                             \
    __builtin_amdgcn_s_barrier();                                              \
    asm volatile("" ::: "memory");                                             \
  } while (0)

#define VMC6 asm volatile("s_waitcnt vmcnt(6)" ::: "memory")
#define VMC0 asm volatile("s_waitcnt vmcnt(0)" ::: "memory")

#define PH(READS, STAGES, MQ, NQ, AF, BF, FENCE) do {                          \
    READS;                                                                     \
    STAGES;                                                                    \
    BAR;                                                                       \
    __builtin_amdgcn_s_setprio(1);                                             \
    MFMA_Q(MQ, NQ, AF, BF);                                                    \
    __builtin_amdgcn_s_setprio(0);                                             \
    FENCE;                                                                     \
    BAR;                                                                       \
  } while (0)

// One K-step (BK=64) on buffer BUF (other = OB), processing tile T.
#define HALF_STG(BUF, OB, T)                                                   \
    PH(READ_A(af, BUF, 0); READ_B(bf0, BUF, 0), STG_B(OB, 0, (T) + 1), 0, 0, af, bf0, ); \
    PH(READ_B(bf1, BUF, 1), STG_A(BUF, 0, (T) + 2), 0, 1, af, bf1, );          \
    PH(READ_A(af, BUF, 1), , 1, 1, af, bf1, );                                 \
    PH(READ_B(bf0, BUF, 0), STG_B(BUF, 1, (T) + 2); STG_A(BUF, 1, (T) + 2), 1, 0, af, bf0, VMC6);

#define HALF_T1(BUF, OB, T)                                                    \
    PH(READ_A(af, BUF, 0); READ_B(bf0, BUF, 0), STG_B(OB, 0, (T) + 1), 0, 0, af, bf0, ); \
    PH(READ_B(bf1, BUF, 1), , 0, 1, af, bf1, );                                \
    PH(READ_A(af, BUF, 1), , 1, 1, af, bf1, );                                 \
    PH(READ_B(bf0, BUF, 0), , 1, 0, af, bf0, VMC0);

#define HALF_T2(BUF)                                                           \
    PH(READ_A(af, BUF, 0); READ_B(bf0, BUF, 0), , 0, 0, af, bf0, );            \
    PH(READ_B(bf1, BUF, 1), , 0, 1, af, bf1, );                                \
    PH(READ_A(af, BUF, 1), , 1, 1, af, bf1, );                                 \
    PH(READ_B(bf0, BUF, 0), , 1, 0, af, bf0, );

#define GEMM8_CORE(A_, LDA_, B_, LDB_, NT_)                                    \
  extern __shared__ char smem[];                                               \
  char* const lsA = smem;                                                      \
  char* const lsB = smem + 65536;                                              \
  const int tid = threadIdx.x;                                                 \
  const int lane = tid & 63;                                                   \
  const int wid = tid >> 6;                                                    \
  const int wr = wid >> 2;                                                     \
  const int wc = wid & 3;                                                      \
  const int fr = lane & 15;                                                    \
  const int kg2 = ((lane >> 4) & 3) << 4;                                      \
  const int lmask = (fr & 6) << 4;                                             \
  f32x4 acc[2][4][2][2];                                                       \
  _Pragma("unroll") for (int a_ = 0; a_ < 2; ++a_)                             \
  _Pragma("unroll") for (int b_ = 0; b_ < 4; ++b_)                             \
  _Pragma("unroll") for (int c_ = 0; c_ < 2; ++c_)                             \
  _Pragma("unroll") for (int d_ = 0; d_ < 2; ++d_)                             \
    acc[a_][b_][c_][d_] = (f32x4){0.f, 0.f, 0.f, 0.f};                         \
  bf16x8 af[4][2], bf0[2][2], bf1[2][2];                                       \
  const unsigned short* sA[2][2];                                              \
  const unsigned short* sB[2][2];                                              \
  _Pragma("unroll") for (int c_ = 0; c_ < 2; ++c_) {                           \
    int d_ = (tid + 512 * c_) * 16;                                            \
    int p_ = d_ ^ (((d_ >> 8) & 3) << 5);                                      \
    int prow = p_ >> 7, pcol = (p_ & 127) >> 1;                                \
    _Pragma("unroll") for (int s_ = 0; s_ < 2; ++s_) {                         \
      int grA = m0 + ((prow >> 6) & 1) * 128 + s_ * 64 + (prow & 63);          \
      sA[s_][c_] = (A_) + (size_t)grA * (LDA_) + pcol;                         \
      int grB = n0 + (prow >> 5) * 64 + s_ * 32 + (prow & 31);                 \
      sB[s_][c_] = (B_) + (size_t)grB * (LDB_) + pcol;                         \
    }                                                                          \
  }                                                                            \
  /* prologue: buf0 full tile0 (8), buf1 {A0,B1,A1} tile1 (6); buf1.B0 is */   \
  /* staged at K-step0.ph1. vmcnt(6) leaves buf1's 6 in flight. */             \
  STG_A(0, 0, 0); STG_B(0, 0, 0); STG_B(0, 1, 0); STG_A(0, 1, 0);              \
  STG_A(1, 0, 1); STG_B(1, 1, 1); STG_A(1, 1, 1);                              \
  VMC6;                                                                        \
  __builtin_amdgcn_s_barrier();                                                \
  asm volatile("" ::: "memory");                                               \
  const int niter = (NT_) / 2;                                                 \
  for (int I = 0; I < niter - 1; ++I) {                                        \
    const int t = 2 * I;                                                       \
    HALF_STG(0, 1, t)                                                          \
    HALF_STG(1, 0, t + 1)                                                      \
  }                                                                            \
  HALF_T1(0, 1, (NT_) - 2)                                                     \
  HALF_T2(1)

// ---------------- GEMM1: acc = Xb @ Wcat^T, fused SwiGLU epilogue ----------
__global__ __launch_bounds__(512)
__attribute__((amdgpu_waves_per_eu(1, 2))) void gemm_swiglu(
    const unsigned short* __restrict__ Xb,
    const unsigned short* __restrict__ Wcat,
    unsigned short* __restrict__ Act) {
    const int NWG = (TT / 256) * (NCAT / 256);  // 16*112 = 1792
    int lid = (blockIdx.x & 7) * (NWG / 8) + (blockIdx.x >> 3);
    const int m0 = (lid & 15) * 256;   // tm fast: weight panel reused across XCD chunk
    const int n0 = (lid >> 4) * 256;

    GEMM8_CORE(Xb, HH, Wcat, HH, HH / 64)

    const int dm = ((lane >> 4) & 3) * 4;
    const int dn = lane & 15;
#pragma unroll
    for (int mq = 0; mq < 2; ++mq)
#pragma unroll
        for (int i = 0; i < 4; ++i)
#pragma unroll
            for (int nq = 0; nq < 2; ++nq) {
                int rowb = m0 + wr * 128 + mq * 64 + i * 16 + dm;
                int col = (n0 + wc * 64 + nq * 32) / 2 + dn;
                f32x4 g4 = acc[mq][i][nq][0];
                f32x4 u4 = acc[mq][i][nq][1];
#pragma unroll
                for (int r = 0; r < 4; ++r) {
                    float g = g4[r], u = u4[r];
                    float s = g * u / (1.0f + __expf(-g));
                    Act[(size_t)(rowb + r) * FF + col] = f32_to_bf16(s);
                }
            }
}

// ---------------- GEMM2: Out = Act @ W2b^T ----------------------------------
__global__ __launch_bounds__(512)
__attribute__((amdgpu_waves_per_eu(1, 2))) void gemm_down(
    const unsigned short* __restrict__ Act,
    const unsigned short* __restrict__ W2b,
    float* __restrict__ Out) {
    const int NWG = (TT / 256) * (HH / 256);  // 16*16 = 256
    int lid = (blockIdx.x & 7) * (NWG / 8) + (blockIdx.x >> 3);
    const int m0 = (lid & 15) * 256;
    const int n0 = (lid >> 4) * 256;

    GEMM8_CORE(Act, FF, W2b, FF, FF / 64)

    const int dm = ((lane >> 4) & 3) * 4;
    const int dn = lane & 15;
#pragma unroll
    for (int mq = 0; mq < 2; ++mq)
#pragma unroll
        for (int i = 0; i < 4; ++i)
#pragma unroll
            for (int nq = 0; nq < 2; ++nq)
#pragma unroll
                for (int j = 0; j < 2; ++j) {
                    int rowb = m0 + wr * 128 + mq * 64 + i * 16 + dm;
                    int col = n0 + wc * 64 + nq * 32 + j * 16 + dn;
                    f32x4 v = acc[mq][i][nq][j];
#pragma unroll
                    for (int r = 0; r < 4; ++r)
                        Out[(size_t)(rowb + r) * HH + col] = v[r];
                }
}

extern "C" void kernel_launch(void* const* d_in, const int* in_sizes, int n_in,
                              void* d_out, int out_size, void* d_ws, size_t ws_size,
                              hipStream_t stream) {
    const float* x  = (const float*)d_in[0];
    const float* w1 = (const float*)d_in[1];
    const float* v1 = (const float*)d_in[2];
    const float* w2 = (const float*)d_in[3];
    float* out = (float*)d_out;

    unsigned short* xb   = (unsigned short*)d_ws;               // [T][H]
    unsigned short* wcat = xb + (size_t)TT * HH;                // [2F][H]
    unsigned short* w2b  = wcat + (size_t)NCAT * HH;            // [H][F]
    unsigned short* act  = w2b + (size_t)HH * FF;               // [T][F]

    hipFuncSetAttribute((const void*)gemm_swiglu,
                        hipFuncAttributeMaxDynamicSharedMemorySize, 131072);
    hipFuncSetAttribute((const void*)gemm_down,
                        hipFuncAttributeMaxDynamicSharedMemorySize, 131072);

    cvt_lin<<<2048, 256, 0, stream>>>(x, xb, (long)TT * HH / 4);
    cvt_lin<<<2048, 256, 0, stream>>>(w2, w2b, (long)HH * FF / 4);
    cvt_tri<<<(HH / 64) * (FF / 64), 256, 0, stream>>>(w1, wcat, 0);
    cvt_tri<<<(HH / 64) * (FF / 64), 256, 0, stream>>>(v1, wcat, 16);

    gemm_swiglu<<<(TT / 256) * (NCAT / 256), 512, 131072, stream>>>(xb, wcat, act);
    gemm_down<<<(TT / 256) * (HH / 256), 512, 131072, stream>>>(act, w2b, out);
}

// Round 8
// 1345.022 us; speedup vs baseline: 1.7515x; 1.0209x over previous
//
#include <hip/hip_runtime.h>
#include <hip/hip_bf16.h>
#include <stdint.h>

#define TT 4096
#define HH 4096
#define FF 14336
#define NCAT (2 * FF)   // 28672

typedef __attribute__((ext_vector_type(8))) short bf16x8;
typedef __attribute__((ext_vector_type(4))) float f32x4;

__device__ __forceinline__ unsigned short f32_to_bf16(float f) {
    union { float f; unsigned int u; } v; v.f = f;
    unsigned int r = v.u + 0x7FFFu + ((v.u >> 16) & 1u);  // RNE
    return (unsigned short)(r >> 16);
}

#define GLOAD16(g, l)                                                          \
    __builtin_amdgcn_global_load_lds(                                          \
        (const __attribute__((address_space(1))) void*)(g),                    \
        (__attribute__((address_space(3))) void*)(l), 16, 0, 0)

// ---------------- convert fp32 -> bf16, same layout ----------------
__global__ void cvt_lin(const float* __restrict__ in,
                        unsigned short* __restrict__ out, long n4) {
    long stride = (long)gridDim.x * blockDim.x;
    for (long i = (long)blockIdx.x * blockDim.x + threadIdx.x; i < n4; i += stride) {
        float4 v = *(const float4*)(in + i * 4);
        ushort4 o;
        o.x = f32_to_bf16(v.x); o.y = f32_to_bf16(v.y);
        o.z = f32_to_bf16(v.z); o.w = f32_to_bf16(v.w);
        *(ushort4*)(out + i * 4) = o;
    }
}

// ---- convert + transpose + interleave: in [H][F] fp32 -> wcat rows bf16 ----
// f-column f of `in` goes to wcat row ((f>>4)<<5) + (f&15) + off   (off=0 gate, 16 up)
__global__ void cvt_tri(const float* __restrict__ in,
                        unsigned short* __restrict__ out, int off) {
    __shared__ float tile[64][65];
    int bh = blockIdx.x & 63;   // H/64 = 64
    int bf = blockIdx.x >> 6;   // F/64 = 224
    int t = threadIdx.x;
    int r16 = t >> 4;           // 0..15
    int c4 = (t & 15) * 4;      // 0..60
#pragma unroll
    for (int it = 0; it < 4; ++it) {
        int h = r16 + it * 16;
        float4 v = *(const float4*)(in + (size_t)(bh * 64 + h) * FF + bf * 64 + c4);
        tile[h][c4 + 0] = v.x; tile[h][c4 + 1] = v.y;
        tile[h][c4 + 2] = v.z; tile[h][c4 + 3] = v.w;
    }
    __syncthreads();
#pragma unroll
    for (int it = 0; it < 4; ++it) {
        int f = r16 + it * 16;
        int fg = bf * 64 + f;
        int row_out = ((fg >> 4) << 5) + (fg & 15) + off;
        ushort4 o;
        o.x = f32_to_bf16(tile[c4 + 0][f]);
        o.y = f32_to_bf16(tile[c4 + 1][f]);
        o.z = f32_to_bf16(tile[c4 + 2][f]);
        o.w = f32_to_bf16(tile[c4 + 3][f]);
        *(ushort4*)(out + (size_t)row_out * HH + bh * 64 + c4) = o;
    }
}

// =================== 8-phase 256x256 GEMM core (BK=64, 8 waves) ============
// LDS: lsA[2buf][2mhalf][128][64]b16 (16KiB slots), lsB same. 128 KiB total.
// Swizzle: byte ^= ((row&6)<<4)  (applied to gload SOURCE and ds_read; LDS linear).
// Register budget model (rounds 4-7, confirmed): acc = 128 AGPRs; 2 waves/EU
// -> 256 unified budget -> arch-VGPR hard cap 128. Held fragments: af (32,
// overwritten in place) + bf1 (16, one barrier) -> no spill (r7: WRITE_SIZE
// exactly = act ideal). Holding 64 (r6) spills ~32MB.
// Snake order (m0n0)->(m0n1)->(m1n1)->(m1n0); B0 re-read from LDS at ph4.
// ds_reads per phase: 12 / 4 / 8 / 4 = 28 per K-step.
// ONE barrier per phase (r8 change): WAR safety needs only the end-of-phase
// barrier — a slot's reader waits lgkmcnt before its own MFMA, which precedes
// its barrier arrival, which precedes any wave's next-phase stage ISSUE; the
// staged DATA lands >= one full K-step later, gated by vmcnt(6)+BAR. RAW
// (stage -> read) unchanged: fence at ph4 + K-step boundary barrier.
// Stage map:  ph1 -> OTHER.B0 t+1 | ph2 -> OWN.A0 t+2 | ph4 -> OWN.B1+A1 t+2.
// Fence vmcnt(6) at ph4 only; prologue 14 loads + vmcnt(6); tail drains 0.

#define STG_A(BUF, SLOT, TILE) do {                                            \
    char* d_ = lsA + (((BUF)*2 + (SLOT)) << 14) + tid * 16;                    \
    GLOAD16(sA[SLOT][0] + (size_t)(TILE) * 64, d_);                            \
    GLOAD16(sA[SLOT][1] + (size_t)(TILE) * 64, d_ + 8192);                     \
  } while (0)

#define STG_B(BUF, SLOT, TILE) do {                                            \
    char* d_ = lsB + (((BUF)*2 + (SLOT)) << 14) + tid * 16;                    \
    GLOAD16(sB[SLOT][0] + (size_t)(TILE) * 64, d_);                            \
    GLOAD16(sB[SLOT][1] + (size_t)(TILE) * 64, d_ + 8192);                     \
  } while (0)

#define READ_A(DST, BUF, MQ) do {                                              \
    const char* pA_ = lsA + (((BUF)*2 + (MQ)) << 14);                          \
    _Pragma("unroll") for (int i_ = 0; i_ < 4; ++i_)                           \
    _Pragma("unroll") for (int k_ = 0; k_ < 2; ++k_)                           \
      DST[i_][k_] = *(const bf16x8*)(pA_ + ((((wr*64 + i_*16 + fr) << 7) + k_*64 + kg2) ^ lmask)); \
  } while (0)

#define READ_B(DST, BUF, NQ) do {                                              \
    const char* pB_ = lsB + (((BUF)*2 + (NQ)) << 14);                          \
    _Pragma("unroll") for (int j_ = 0; j_ < 2; ++j_)                           \
    _Pragma("unroll") for (int k_ = 0; k_ < 2; ++k_)                           \
      DST[j_][k_] = *(const bf16x8*)(pB_ + ((((wc*32 + j_*16 + fr) << 7) + k_*64 + kg2) ^ lmask)); \
  } while (0)

#define MFMA_Q(MQ, NQ, AF, BF)                                                 \
    _Pragma("unroll") for (int i_ = 0; i_ < 4; ++i_)                           \
    _Pragma("unroll") for (int j_ = 0; j_ < 2; ++j_)                           \
    _Pragma("unroll") for (int k_ = 0; k_ < 2; ++k_)                           \
      acc[MQ][i_][NQ][j_] = __builtin_amdgcn_mfma_f32_16x16x32_bf16(           \
          AF[i_][k_], BF[j_][k_], acc[MQ][i_][NQ][j_], 0, 0, 0)

#define BAR do {                                                               \
    asm volatile("" ::: "memory");                                             \
    __builtin_amdgcn_s_barrier();                                              \
    asm volatile("" ::: "memory");                                             \
  } while (0)

#define VMC6 asm volatile("s_waitcnt vmcnt(6)" ::: "memory")
#define VMC0 asm volatile("s_waitcnt vmcnt(0)" ::: "memory")

// Single barrier per phase (see ledger above).
#define PH(READS, STAGES, MQ, NQ, AF, BF, FENCE) do {                          \
    READS;                                                                     \
    STAGES;                                                                    \
    __builtin_amdgcn_s_setprio(1);                                             \
    MFMA_Q(MQ, NQ, AF, BF);                                                    \
    __builtin_amdgcn_s_setprio(0);                                             \
    FENCE;                                                                     \
    BAR;                                                                       \
  } while (0)

// One K-step (BK=64) on buffer BUF (other = OB), processing tile T.
#define HALF_STG(BUF, OB, T)                                                   \
    PH(READ_A(af, BUF, 0); READ_B(bf0, BUF, 0), STG_B(OB, 0, (T) + 1), 0, 0, af, bf0, ); \
    PH(READ_B(bf1, BUF, 1), STG_A(BUF, 0, (T) + 2), 0, 1, af, bf1, );          \
    PH(READ_A(af, BUF, 1), , 1, 1, af, bf1, );                                 \
    PH(READ_B(bf0, BUF, 0), STG_B(BUF, 1, (T) + 2); STG_A(BUF, 1, (T) + 2), 1, 0, af, bf0, VMC6);

#define HALF_T1(BUF, OB, T)                                                    \
    PH(READ_A(af, BUF, 0); READ_B(bf0, BUF, 0), STG_B(OB, 0, (T) + 1), 0, 0, af, bf0, ); \
    PH(READ_B(bf1, BUF, 1), , 0, 1, af, bf1, );                                \
    PH(READ_A(af, BUF, 1), , 1, 1, af, bf1, );                                 \
    PH(READ_B(bf0, BUF, 0), , 1, 0, af, bf0, VMC0);

#define HALF_T2(BUF)                                                           \
    PH(READ_A(af, BUF, 0); READ_B(bf0, BUF, 0), , 0, 0, af, bf0, );            \
    PH(READ_B(bf1, BUF, 1), , 0, 1, af, bf1, );                                \
    PH(READ_A(af, BUF, 1), , 1, 1, af, bf1, );                                 \
    PH(READ_B(bf0, BUF, 0), , 1, 0, af, bf0, );

#define GEMM8_CORE(A_, LDA_, B_, LDB_, NT_)                                    \
  extern __shared__ char smem[];                                               \
  char* const lsA = smem;                                                      \
  char* const lsB = smem + 65536;                                              \
  const int tid = threadIdx.x;                                                 \
  const int lane = tid & 63;                                                   \
  const int wid = tid >> 6;                                                    \
  const int wr = wid >> 2;                                                     \
  const int wc = wid & 3;                                                      \
  const int fr = lane & 15;                                                    \
  const int kg2 = ((lane >> 4) & 3) << 4;                                      \
  const int lmask = (fr & 6) << 4;                                             \
  f32x4 acc[2][4][2][2];                                                       \
  _Pragma("unroll") for (int a_ = 0; a_ < 2; ++a_)                             \
  _Pragma("unroll") for (int b_ = 0; b_ < 4; ++b_)                             \
  _Pragma("unroll") for (int c_ = 0; c_ < 2; ++c_)                             \
  _Pragma("unroll") for (int d_ = 0; d_ < 2; ++d_)                             \
    acc[a_][b_][c_][d_] = (f32x4){0.f, 0.f, 0.f, 0.f};                         \
  bf16x8 af[4][2], bf0[2][2], bf1[2][2];                                       \
  const unsigned short* sA[2][2];                                              \
  const unsigned short* sB[2][2];                                              \
  _Pragma("unroll") for (int c_ = 0; c_ < 2; ++c_) {                           \
    int d_ = (tid + 512 * c_) * 16;                                            \
    int p_ = d_ ^ (((d_ >> 8) & 3) << 5);                                      \
    int prow = p_ >> 7, pcol = (p_ & 127) >> 1;                                \
    _Pragma("unroll") for (int s_ = 0; s_ < 2; ++s_) {                         \
      int grA = m0 + ((prow >> 6) & 1) * 128 + s_ * 64 + (prow & 63);          \
      sA[s_][c_] = (A_) + (size_t)grA * (LDA_) + pcol;                         \
      int grB = n0 + (prow >> 5) * 64 + s_ * 32 + (prow & 31);                 \
      sB[s_][c_] = (B_) + (size_t)grB * (LDB_) + pcol;                         \
    }                                                                          \
  }                                                                            \
  /* prologue: buf0 full tile0 (8), buf1 {A0,B1,A1} tile1 (6); buf1.B0 is */   \
  /* staged at K-step0.ph1. vmcnt(6) leaves buf1's 6 in flight. */             \
  STG_A(0, 0, 0); STG_B(0, 0, 0); STG_B(0, 1, 0); STG_A(0, 1, 0);              \
  STG_A(1, 0, 1); STG_B(1, 1, 1); STG_A(1, 1, 1);                              \
  VMC6;                                                                        \
  __builtin_amdgcn_s_barrier();                                                \
  asm volatile("" ::: "memory");                                               \
  const int niter = (NT_) / 2;                                                 \
  for (int I = 0; I < niter - 1; ++I) {                                        \
    const int t = 2 * I;                                                       \
    HALF_STG(0, 1, t)                                                          \
    HALF_STG(1, 0, t + 1)                                                      \
  }                                                                            \
  HALF_T1(0, 1, (NT_) - 2)                                                     \
  HALF_T2(1)

// ---------------- GEMM1: acc = Xb @ Wcat^T, fused SwiGLU epilogue ----------
__global__ __launch_bounds__(512)
__attribute__((amdgpu_waves_per_eu(1, 2))) void gemm_swiglu(
    const unsigned short* __restrict__ Xb,
    const unsigned short* __restrict__ Wcat,
    unsigned short* __restrict__ Act) {
    const int NWG = (TT / 256) * (NCAT / 256);  // 16*112 = 1792
    int lid = (blockIdx.x & 7) * (NWG / 8) + (blockIdx.x >> 3);
    const int m0 = (lid & 15) * 256;   // tm fast: weight panel reused across XCD chunk
    const int n0 = (lid >> 4) * 256;

    GEMM8_CORE(Xb, HH, Wcat, HH, HH / 64)

    const int dm = ((lane >> 4) & 3) * 4;
    const int dn = lane & 15;
#pragma unroll
    for (int mq = 0; mq < 2; ++mq)
#pragma unroll
        for (int i = 0; i < 4; ++i)
#pragma unroll
            for (int nq = 0; nq < 2; ++nq) {
                int rowb = m0 + wr * 128 + mq * 64 + i * 16 + dm;
                int col = (n0 + wc * 64 + nq * 32) / 2 + dn;
                f32x4 g4 = acc[mq][i][nq][0];
                f32x4 u4 = acc[mq][i][nq][1];
#pragma unroll
                for (int r = 0; r < 4; ++r) {
                    float g = g4[r], u = u4[r];
                    float s = g * u / (1.0f + __expf(-g));
                    Act[(size_t)(rowb + r) * FF + col] = f32_to_bf16(s);
                }
            }
}

// ---------------- GEMM2: Out = Act @ W2b^T ----------------------------------
__global__ __launch_bounds__(512)
__attribute__((amdgpu_waves_per_eu(1, 2))) void gemm_down(
    const unsigned short* __restrict__ Act,
    const unsigned short* __restrict__ W2b,
    float* __restrict__ Out) {
    const int NWG = (TT / 256) * (HH / 256);  // 16*16 = 256
    int lid = (blockIdx.x & 7) * (NWG / 8) + (blockIdx.x >> 3);
    const int m0 = (lid & 15) * 256;
    const int n0 = (lid >> 4) * 256;

    GEMM8_CORE(Act, FF, W2b, FF, FF / 64)

    const int dm = ((lane >> 4) & 3) * 4;
    const int dn = lane & 15;
#pragma unroll
    for (int mq = 0; mq < 2; ++mq)
#pragma unroll
        for (int i = 0; i < 4; ++i)
#pragma unroll
            for (int nq = 0; nq < 2; ++nq)
#pragma unroll
                for (int j = 0; j < 2; ++j) {
                    int rowb = m0 + wr * 128 + mq * 64 + i * 16 + dm;
                    int col = n0 + wc * 64 + nq * 32 + j * 16 + dn;
                    f32x4 v = acc[mq][i][nq][j];
#pragma unroll
                    for (int r = 0; r < 4; ++r)
                        Out[(size_t)(rowb + r) * HH + col] = v[r];
                }
}

extern "C" void kernel_launch(void* const* d_in, const int* in_sizes, int n_in,
                              void* d_out, int out_size, void* d_ws, size_t ws_size,
                              hipStream_t stream) {
    const float* x  = (const float*)d_in[0];
    const float* w1 = (const float*)d_in[1];
    const float* v1 = (const float*)d_in[2];
    const float* w2 = (const float*)d_in[3];
    float* out = (float*)d_out;

    unsigned short* xb   = (unsigned short*)d_ws;               // [T][H]
    unsigned short* wcat = xb + (size_t)TT * HH;                // [2F][H]
    unsigned short* w2b  = wcat + (size_t)NCAT * HH;            // [H][F]
    unsigned short* act  = w2b + (size_t)HH * FF;               // [T][F]

    hipFuncSetAttribute((const void*)gemm_swiglu,
                        hipFuncAttributeMaxDynamicSharedMemorySize, 131072);
    hipFuncSetAttribute((const void*)gemm_down,
                        hipFuncAttributeMaxDynamicSharedMemorySize, 131072);

    cvt_lin<<<2048, 256, 0, stream>>>(x, xb, (long)TT * HH / 4);
    cvt_lin<<<2048, 256, 0, stream>>>(w2, w2b, (long)HH * FF / 4);
    cvt_tri<<<(HH / 64) * (FF / 64), 256, 0, stream>>>(w1, wcat, 0);
    cvt_tri<<<(HH / 64) * (FF / 64), 256, 0, stream>>>(v1, wcat, 16);

    gemm_swiglu<<<(TT / 256) * (NCAT / 256), 512, 131072, stream>>>(xb, wcat, act);
    gemm_down<<<(TT / 256) * (HH / 256), 512, 131072, stream>>>(act, w2b, out);
}

// Round 9
// 1299.861 us; speedup vs baseline: 1.8124x; 1.0347x over previous
//
#include <hip/hip_runtime.h>
#include <hip/hip_bf16.h>
#include <stdint.h>

#define TT 4096
#define HH 4096
#define FF 14336
#define NCAT (2 * FF)   // 28672

typedef __attribute__((ext_vector_type(8))) short bf16x8;
typedef __attribute__((ext_vector_type(4))) float f32x4;

__device__ __forceinline__ unsigned short f32_to_bf16(float f) {
    union { float f; unsigned int u; } v; v.f = f;
    unsigned int r = v.u + 0x7FFFu + ((v.u >> 16) & 1u);  // RNE
    return (unsigned short)(r >> 16);
}

#define GLOAD16(g, l)                                                          \
    __builtin_amdgcn_global_load_lds(                                          \
        (const __attribute__((address_space(1))) void*)(g),                    \
        (__attribute__((address_space(3))) void*)(l), 16, 0, 0)

// ---------------- convert fp32 -> bf16, same layout ----------------
__global__ void cvt_lin(const float* __restrict__ in,
                        unsigned short* __restrict__ out, long n4) {
    long stride = (long)gridDim.x * blockDim.x;
    for (long i = (long)blockIdx.x * blockDim.x + threadIdx.x; i < n4; i += stride) {
        float4 v = *(const float4*)(in + i * 4);
        ushort4 o;
        o.x = f32_to_bf16(v.x); o.y = f32_to_bf16(v.y);
        o.z = f32_to_bf16(v.z); o.w = f32_to_bf16(v.w);
        *(ushort4*)(out + i * 4) = o;
    }
}

// ---- convert + transpose + interleave: in [H][F] fp32 -> wcat rows bf16 ----
__global__ void cvt_tri(const float* __restrict__ in,
                        unsigned short* __restrict__ out, int off) {
    __shared__ float tile[64][65];
    int bh = blockIdx.x & 63;   // H/64 = 64
    int bf = blockIdx.x >> 6;   // F/64 = 224
    int t = threadIdx.x;
    int r16 = t >> 4;           // 0..15
    int c4 = (t & 15) * 4;      // 0..60
#pragma unroll
    for (int it = 0; it < 4; ++it) {
        int h = r16 + it * 16;
        float4 v = *(const float4*)(in + (size_t)(bh * 64 + h) * FF + bf * 64 + c4);
        tile[h][c4 + 0] = v.x; tile[h][c4 + 1] = v.y;
        tile[h][c4 + 2] = v.z; tile[h][c4 + 3] = v.w;
    }
    __syncthreads();
#pragma unroll
    for (int it = 0; it < 4; ++it) {
        int f = r16 + it * 16;
        int fg = bf * 64 + f;
        int row_out = ((fg >> 4) << 5) + (fg & 15) + off;
        ushort4 o;
        o.x = f32_to_bf16(tile[c4 + 0][f]);
        o.y = f32_to_bf16(tile[c4 + 1][f]);
        o.z = f32_to_bf16(tile[c4 + 2][f]);
        o.w = f32_to_bf16(tile[c4 + 3][f]);
        *(ushort4*)(out + (size_t)row_out * HH + bh * 64 + c4) = o;
    }
}

// =================== 8-phase 256x256 GEMM core (BK=64, 8 waves) ============
// LDS: A slots at smem[0..64K): [2buf][2mhalf][128][64]b16; B at smem+64K.
// Swizzle byte ^= ((row&6)<<4) on gload SOURCE + ds_read (LDS linear).
// r9 schedule: hold af(32, in-place) + bfA(16, B0 resident) + bfB(16, B1).
// 24 ds_reads/K-step balanced 8/4/8/4 (ph4 prefetches NEXT K-step's B0).
// Snake (m0n0)->(m0n1)->(m1n1)->(m1n0).
// Slot last-reads: A0 ph1, B1 ph2, A1 ph3, B0 prev-K ph4 (prefetch).
// Stage map, ALL own-buffer tile t+2: ph2<-A0+B0, ph3<-B1, ph4<-A1; each
// slot's stage issues >=1 barrier after its last read.  Staged data is read
// TWO K-steps after issue (other buffer's K-step intervenes) -> ~1700 cyc
// HBM slack.  vmcnt(8) at each K-step end drains the older group (the buffer
// about to be read next), leaves this K-step's 8 in flight.  ph4 prefetch of
// OB.B0 sits after the fence -> its data (older group) has landed.
// Register budget (cap 128 arch: acc=128 AGPR + 256/wave @2 waves/EU): held
// 64 + 32-bit stage offsets (8) + addressing -> fits; spill shows in WRITE_SIZE.

#define STG_A(BUF, SLOT, T) do {                                               \
    char* d_ = (char*)smem + (((BUF)*2 + (SLOT)) << 14) + tid * 16;            \
    GLOAD16(Abase + (size_t)(oA[SLOT][0] + (unsigned)(T) * 128), d_);          \
    GLOAD16(Abase + (size_t)(oA[SLOT][1] + (unsigned)(T) * 128), d_ + 8192);   \
  } while (0)

#define STG_B(BUF, SLOT, T) do {                                               \
    char* d_ = (char*)smem + 65536 + (((BUF)*2 + (SLOT)) << 14) + tid * 16;    \
    GLOAD16(Bbase + (size_t)(oB[SLOT][0] + (unsigned)(T) * 128), d_);          \
    GLOAD16(Bbase + (size_t)(oB[SLOT][1] + (unsigned)(T) * 128), d_ + 8192);   \
  } while (0)

#define READ_A(DST, BUF, MQ) do {                                              \
    const char* pA_ = (const char*)smem + (((BUF)*2 + (MQ)) << 14);            \
    _Pragma("unroll") for (int i_ = 0; i_ < 4; ++i_)                           \
    _Pragma("unroll") for (int k_ = 0; k_ < 2; ++k_)                           \
      DST[i_][k_] = *(const bf16x8*)(pA_ + ((((wr*64 + i_*16 + fr) << 7) + k_*64 + kg2) ^ lmask)); \
  } while (0)

#define READ_B(DST, BUF, NQ) do {                                              \
    const char* pB_ = (const char*)smem + 65536 + (((BUF)*2 + (NQ)) << 14);    \
    _Pragma("unroll") for (int j_ = 0; j_ < 2; ++j_)                           \
    _Pragma("unroll") for (int k_ = 0; k_ < 2; ++k_)                           \
      DST[j_][k_] = *(const bf16x8*)(pB_ + ((((wc*32 + j_*16 + fr) << 7) + k_*64 + kg2) ^ lmask)); \
  } while (0)

#define MFMA_Q(MQ, NQ, AF, BF)                                                 \
    _Pragma("unroll") for (int i_ = 0; i_ < 4; ++i_)                           \
    _Pragma("unroll") for (int j_ = 0; j_ < 2; ++j_)                           \
    _Pragma("unroll") for (int k_ = 0; k_ < 2; ++k_)                           \
      acc[MQ][i_][NQ][j_] = __builtin_amdgcn_mfma_f32_16x16x32_bf16(           \
          AF[i_][k_], BF[j_][k_], acc[MQ][i_][NQ][j_], 0, 0, 0)

#define BAR do {                                                               \
    asm volatile("" ::: "memory");                                             \
    __builtin_amdgcn_s_barrier();                                              \
    asm volatile("" ::: "memory");                                             \
  } while (0)

#define VMC8 asm volatile("s_waitcnt vmcnt(8)" ::: "memory")
#define VMC0 asm volatile("s_waitcnt vmcnt(0)" ::: "memory")

#define PHX(READS, STAGES, MQ, NQ, AF, BF, FENCE, POST) do {                   \
    READS;                                                                     \
    STAGES;                                                                    \
    __builtin_amdgcn_s_setprio(1);                                             \
    MFMA_Q(MQ, NQ, AF, BF);                                                    \
    __builtin_amdgcn_s_setprio(0);                                             \
    FENCE;                                                                     \
    POST;                                                                      \
    BAR;                                                                       \
  } while (0)

#define PH(READS, STAGES, MQ, NQ, AF, BF, FENCE)                               \
    PHX(READS, STAGES, MQ, NQ, AF, BF, FENCE, )

// One K-step (BK=64) on buffer BUF (other OB); stages own tile TS = t+2.
#define HALF_STG(BUF, OB, TS)                                                  \
    PH(READ_A(af, BUF, 0), , 0, 0, af, bfA, );                                 \
    PH(READ_B(bfB, BUF, 1), STG_A(BUF, 0, TS); STG_B(BUF, 0, TS), 0, 1, af, bfB, ); \
    PH(READ_A(af, BUF, 1), STG_B(BUF, 1, TS), 1, 1, af, bfB, );                \
    PHX(, STG_A(BUF, 1, TS), 1, 0, af, bfA, VMC8, READ_B(bfA, OB, 0));

#define HALF_T1(BUF, OB)                                                       \
    PH(READ_A(af, BUF, 0), , 0, 0, af, bfA, );                                 \
    PH(READ_B(bfB, BUF, 1), , 0, 1, af, bfB, );                                \
    PH(READ_A(af, BUF, 1), , 1, 1, af, bfB, );                                 \
    PHX(, , 1, 0, af, bfA, VMC0, READ_B(bfA, OB, 0));

#define HALF_T2(BUF)                                                           \
    PH(READ_A(af, BUF, 0), , 0, 0, af, bfA, );                                 \
    PH(READ_B(bfB, BUF, 1), , 0, 1, af, bfB, );                                \
    PH(READ_A(af, BUF, 1), , 1, 1, af, bfB, );                                 \
    PHX(, , 1, 0, af, bfA, , );

#define GEMM8_CORE(A_, LDA_, B_, LDB_, NT_)                                    \
  extern __shared__ char smem[];                                               \
  const char* const Abase = (const char*)(A_);                                 \
  const char* const Bbase = (const char*)(B_);                                 \
  const int tid = threadIdx.x;                                                 \
  const int lane = tid & 63;                                                   \
  const int wid = tid >> 6;                                                    \
  const int wr = wid >> 2;                                                     \
  const int wc = wid & 3;                                                      \
  const int fr = lane & 15;                                                    \
  const int kg2 = ((lane >> 4) & 3) << 4;                                      \
  const int lmask = (fr & 6) << 4;                                             \
  f32x4 acc[2][4][2][2];                                                       \
  _Pragma("unroll") for (int a_ = 0; a_ < 2; ++a_)                             \
  _Pragma("unroll") for (int b_ = 0; b_ < 4; ++b_)                             \
  _Pragma("unroll") for (int c_ = 0; c_ < 2; ++c_)                             \
  _Pragma("unroll") for (int d_ = 0; d_ < 2; ++d_)                             \
    acc[a_][b_][c_][d_] = (f32x4){0.f, 0.f, 0.f, 0.f};                         \
  bf16x8 af[4][2], bfA[2][2], bfB[2][2];                                       \
  unsigned int oA[2][2], oB[2][2];                                             \
  _Pragma("unroll") for (int c_ = 0; c_ < 2; ++c_) {                           \
    int d_ = (tid + 512 * c_) * 16;                                            \
    int p_ = d_ ^ (((d_ >> 8) & 3) << 5);                                      \
    int prow = p_ >> 7, pcol = (p_ & 127) >> 1;                                \
    _Pragma("unroll") for (int s_ = 0; s_ < 2; ++s_) {                         \
      int grA = m0 + ((prow >> 6) & 1) * 128 + s_ * 64 + (prow & 63);          \
      oA[s_][c_] = (unsigned)((size_t)grA * (LDA_) + pcol) * 2u;               \
      int grB = n0 + (prow >> 5) * 64 + s_ * 32 + (prow & 31);                 \
      oB[s_][c_] = (unsigned)((size_t)grB * (LDB_) + pcol) * 2u;               \
    }                                                                          \
  }                                                                            \
  /* prologue: both buffers' 4 slots (16 gloads); drain buf0's 8; preread */   \
  STG_A(0, 0, 0); STG_B(0, 0, 0); STG_B(0, 1, 0); STG_A(0, 1, 0);              \
  STG_A(1, 0, 1); STG_B(1, 0, 1); STG_B(1, 1, 1); STG_A(1, 1, 1);              \
  VMC8;                                                                        \
  __builtin_amdgcn_s_barrier();                                                \
  asm volatile("" ::: "memory");                                               \
  READ_B(bfA, 0, 0);                                                           \
  const int niter = (NT_) / 2;                                                 \
  for (int I = 0; I < niter - 1; ++I) {                                        \
    HALF_STG(0, 1, 2 * I + 2)                                                  \
    HALF_STG(1, 0, 2 * I + 3)                                                  \
  }                                                                            \
  HALF_T1(0, 1)                                                                \
  HALF_T2(1)

// ---------------- GEMM1: acc = Xb @ Wcat^T, fused SwiGLU epilogue ----------
__global__ __launch_bounds__(512)
__attribute__((amdgpu_waves_per_eu(1, 2))) void gemm_swiglu(
    const unsigned short* __restrict__ Xb,
    const unsigned short* __restrict__ Wcat,
    unsigned short* __restrict__ Act) {
    const int NWG = (TT / 256) * (NCAT / 256);  // 16*112 = 1792
    int lid = (blockIdx.x & 7) * (NWG / 8) + (blockIdx.x >> 3);
    const int m0 = (lid & 15) * 256;   // tm fast: weight panel reused across XCD chunk
    const int n0 = (lid >> 4) * 256;

    GEMM8_CORE(Xb, HH, Wcat, HH, HH / 64)

    const int dm = ((lane >> 4) & 3) * 4;
    const int dn = lane & 15;
#pragma unroll
    for (int mq = 0; mq < 2; ++mq)
#pragma unroll
        for (int i = 0; i < 4; ++i)
#pragma unroll
            for (int nq = 0; nq < 2; ++nq) {
                int rowb = m0 + wr * 128 + mq * 64 + i * 16 + dm;
                int col = (n0 + wc * 64 + nq * 32) / 2 + dn;
                f32x4 g4 = acc[mq][i][nq][0];
                f32x4 u4 = acc[mq][i][nq][1];
#pragma unroll
                for (int r = 0; r < 4; ++r) {
                    float g = g4[r], u = u4[r];
                    float s = g * u / (1.0f + __expf(-g));
                    Act[(size_t)(rowb + r) * FF + col] = f32_to_bf16(s);
                }
            }
}

// ---------------- GEMM2: Out = Act @ W2b^T ----------------------------------
__global__ __launch_bounds__(512)
__attribute__((amdgpu_waves_per_eu(1, 2))) void gemm_down(
    const unsigned short* __restrict__ Act,
    const unsigned short* __restrict__ W2b,
    float* __restrict__ Out) {
    const int NWG = (TT / 256) * (HH / 256);  // 16*16 = 256
    int lid = (blockIdx.x & 7) * (NWG / 8) + (blockIdx.x >> 3);
    const int m0 = (lid & 15) * 256;
    const int n0 = (lid >> 4) * 256;

    GEMM8_CORE(Act, FF, W2b, FF, FF / 64)

    const int dm = ((lane >> 4) & 3) * 4;
    const int dn = lane & 15;
#pragma unroll
    for (int mq = 0; mq < 2; ++mq)
#pragma unroll
        for (int i = 0; i < 4; ++i)
#pragma unroll
            for (int nq = 0; nq < 2; ++nq)
#pragma unroll
                for (int j = 0; j < 2; ++j) {
                    int rowb = m0 + wr * 128 + mq * 64 + i * 16 + dm;
                    int col = n0 + wc * 64 + nq * 32 + j * 16 + dn;
                    f32x4 v = acc[mq][i][nq][j];
#pragma unroll
                    for (int r = 0; r < 4; ++r)
                        Out[(size_t)(rowb + r) * HH + col] = v[r];
                }
}

extern "C" void kernel_launch(void* const* d_in, const int* in_sizes, int n_in,
                              void* d_out, int out_size, void* d_ws, size_t ws_size,
                              hipStream_t stream) {
    const float* x  = (const float*)d_in[0];
    const float* w1 = (const float*)d_in[1];
    const float* v1 = (const float*)d_in[2];
    const float* w2 = (const float*)d_in[3];
    float* out = (float*)d_out;

    unsigned short* xb   = (unsigned short*)d_ws;               // [T][H]
    unsigned short* wcat = xb + (size_t)TT * HH;                // [2F][H]
    unsigned short* w2b  = wcat + (size_t)NCAT * HH;            // [H][F]
    unsigned short* act  = w2b + (size_t)HH * FF;               // [T][F]

    hipFuncSetAttribute((const void*)gemm_swiglu,
                        hipFuncAttributeMaxDynamicSharedMemorySize, 131072);
    hipFuncSetAttribute((const void*)gemm_down,
                        hipFuncAttributeMaxDynamicSharedMemorySize, 131072);

    cvt_lin<<<2048, 256, 0, stream>>>(x, xb, (long)TT * HH / 4);
    cvt_lin<<<2048, 256, 0, stream>>>(w2, w2b, (long)HH * FF / 4);
    cvt_tri<<<(HH / 64) * (FF / 64), 256, 0, stream>>>(w1, wcat, 0);
    cvt_tri<<<(HH / 64) * (FF / 64), 256, 0, stream>>>(v1, wcat, 16);

    gemm_swiglu<<<(TT / 256) * (NCAT / 256), 512, 131072, stream>>>(xb, wcat, act);
    gemm_down<<<(TT / 256) * (HH / 256), 512, 131072, stream>>>(act, w2b, out);
}